// Round 5
// baseline (208.192 us; speedup 1.0000x reference)
//
#include <hip/hip_runtime.h>
#include <math.h>

#define NPX 4096          // 64*64 low-res pixels per batch
#define H2 128
#define W2 128

// K1: 1x1 conv (256->64) + BN + ReLU. grid (128 px-chunks of 64, 2 co-halves),
// block 256 = 4 waves. Block stages X[256ci][64px] (64 KB LDS) via linear float4
// copy; wave w computes co = coh*32 + w*8 .. +8 for its 64 px, weights via
// wave-uniform s_load. No atomics, no reduce. X read 2x total.
__global__ __launch_bounds__(256) void k1_conv1x1(
    const float* __restrict__ X, const float* __restrict__ w,
    const float* __restrict__ g, const float* __restrict__ bt,
    const float* __restrict__ m, const float* __restrict__ var,
    float* __restrict__ mid)
{
    __shared__ float xl[256 * 64];   // [ci][px] 64 KB
    int tid = threadIdx.x;
    int lane = tid & 63;
    int wv = __builtin_amdgcn_readfirstlane(tid >> 6);
    int chunk = blockIdx.x;          // 0..127
    int bb = chunk >> 6;
    int px0 = (chunk & 63) * 64;
    int co0 = blockIdx.y * 32 + wv * 8;

    // linear staging: element idx = ci*64 + p  <->  global ci*NPX + px0 + p
    const float4* xg = (const float4*)(X + (size_t)bb * 256 * NPX + px0);
    float4* xl4 = (float4*)xl;
    #pragma unroll
    for (int mm = 0; mm < 16; ++mm) {
        int idx4 = tid + 256 * mm;           // 0..4095
        int ci = idx4 >> 4, p4 = idx4 & 15;
        xl4[idx4] = xg[(size_t)ci * (NPX / 4) + p4];
    }
    __syncthreads();

    const float* wp = w + (size_t)co0 * 256;   // wave-uniform -> s_load
    float acc[8];
    #pragma unroll
    for (int j = 0; j < 8; ++j) acc[j] = 0.f;

    #pragma unroll 4
    for (int ci = 0; ci < 256; ++ci) {
        float x = xl[ci * 64 + lane];
        #pragma unroll
        for (int j = 0; j < 8; ++j)
            acc[j] += x * wp[j * 256 + ci];
    }

    #pragma unroll
    for (int j = 0; j < 8; ++j) {
        int co = co0 + j;
        float inv = g[co] * rsqrtf(var[co] + 1e-5f);
        float a = fmaxf(acc[j] * inv + (bt[co] - m[co] * inv), 0.f);
        mid[((size_t)bb * 64 + co) * NPX + px0 + lane] = a;
    }
}

// K2a: 3x3 conv (64->100) on pre-activated mid. grid (25 co-quads, 16 tiles x 2 b),
// block 256 = 16x16 px, thread = 1 px x 4 co. Weights wave-uniform -> s_load.
// Staging is SHIFT-ONLY: tile [r][ci][c] with r-stride 520 (= 16*32+8), so rows
// start at banks {0,8,16,24} -> exact 2-way LDS access everywhere. Lane geometry
// (c, gx, col-validity) is loop-invariant and hoisted.
__global__ __launch_bounds__(256) void k2a_conv3x3(
    const float* __restrict__ mid, const float* __restrict__ ew,
    float* __restrict__ enc)
{
    __shared__ float mt[18 * 520];   // 37,440 B

    int tid = threadIdx.x;
    int cq = blockIdx.x;             // co = 4*cq + j
    int t = blockIdx.y;
    int bb = t >> 4;
    int tile = t & 15;
    int ty0 = (tile >> 2) * 16, tx0 = (tile & 3) * 16;
    int qy = tid >> 4, qx = tid & 15;

    const float* wbase = ew + (size_t)(4 * cq) * 576;   // [j][ci][k], uniform

    // loop-invariant staging geometry: 32 lanes per row-segment
    int c  = tid & 31;               // padded col 0..31 (c<18 real)
    int gx = tx0 + c - 1;
    bool cok = (c < 18) && ((unsigned)gx < 64u);
    int sub0 = tid >> 5;             // 0..7; sub = r*16+ci advances by 8/iter

    float acc[4] = {0.f, 0.f, 0.f, 0.f};

    for (int cc = 0; cc < 4; ++cc) {
        __syncthreads();
        const float* msrc = mid + ((size_t)bb * 64 + cc * 16) * NPX;
        #pragma unroll
        for (int m2 = 0; m2 < 36; ++m2) {      // 288 row-segments of 32
            int sub = sub0 + m2 * 8;           // r*16 + ci
            int r  = sub >> 4;                 // 0..17
            int ci = sub & 15;
            int gy = ty0 + r - 1;
            float v = 0.f;
            if (cok && (unsigned)gy < 64u)
                v = msrc[((size_t)ci << 12) + (gy << 6) + gx];
            mt[r * 520 + (ci << 5) + c] = v;
        }
        __syncthreads();

        #pragma unroll 2
        for (int ci = 0; ci < 16; ++ci) {
            int base = qy * 520 + (ci << 5) + qx;
            float nb[9];
            #pragma unroll
            for (int dy = 0; dy < 3; ++dy)
                #pragma unroll
                for (int dx = 0; dx < 3; ++dx)
                    nb[dy * 3 + dx] = mt[base + dy * 520 + dx];
            const float* wp = wbase + (cc * 16 + ci) * 9;   // uniform -> s_load
            #pragma unroll
            for (int j = 0; j < 4; ++j)
                #pragma unroll
                for (int k = 0; k < 9; ++k)
                    acc[j] += nb[k] * wp[j * 576 + k];
        }
    }

    int sp = (ty0 + qy) * 64 + tx0 + qx;
    #pragma unroll
    for (int j = 0; j < 4; ++j)
        enc[((size_t)bb * 100 + 4 * cq + j) * NPX + sp] = acc[j];
}

// K2b: BN + clamp + pow + softmax over 25 taps. wn layout [b][s*25+k][px].
__global__ __launch_bounds__(64) void k2b_softmax(
    const float* __restrict__ enc,
    const float* __restrict__ g, const float* __restrict__ bt,
    const float* __restrict__ m, const float* __restrict__ var,
    const float* __restrict__ power_p,
    float* __restrict__ wn)
{
    int s = blockIdx.x & 3;
    int p = (blockIdx.x >> 2) * 64 + threadIdx.x;
    int bb = p >> 12, sp = p & (NPX - 1);
    float pw = fmaxf(power_p[0], 1e-5f);
    float tv[25];
    float mx = -1e30f;
    #pragma unroll
    for (int k = 0; k < 25; ++k) {
        int co = 4 * k + s;
        float inv = g[co] * rsqrtf(var[co] + 1e-5f);
        float e = enc[((size_t)bb * 100 + co) * NPX + sp] * inv + (bt[co] - m[co] * inv);
        e = fmaxf(e, 1e-5f);
        float x = exp2f(pw * log2f(e));
        tv[k] = x;
        mx = fmaxf(mx, x);
    }
    float sum = 0.f;
    #pragma unroll
    for (int k = 0; k < 25; ++k) {
        float e = expf(tv[k] - mx);
        tv[k] = e;
        sum += e;
    }
    float r = 1.0f / sum;
    #pragma unroll
    for (int k = 0; k < 25; ++k)
        wn[((size_t)bb * 100 + s * 25 + k) * NPX + sp] = tv[k] * r;
}

// K3: reassembly. grid (2b x 16 tiles, 16 ch-chunks), block 256 = 16x16 low-res px.
// xt pitch 24 -> 2-way LDS reads.
__global__ __launch_bounds__(256, 2) void k3_carafe(
    const float* __restrict__ X, const float* __restrict__ wn,
    float* __restrict__ out)
{
    __shared__ float xt[16 * 480];   // 16 ch x 20 rows x pitch 24 = 30.7 KB
    int tid = threadIdx.x;
    int bx = blockIdx.x;
    int bb = bx >> 4;
    int t = bx & 15;
    int ty0 = (t >> 2) * 16, tx0 = (t & 3) * 16;
    int c0 = blockIdx.y * 16;
    for (int idx = tid; idx < 7680; idx += 256) {   // 16 ch x 20 x 24
        int ch = idx / 480;
        int rem = idx - ch * 480;
        int r = rem / 24, cc = rem - r * 24;
        int gy = ty0 + r - 2, gx = tx0 + cc - 2;
        float val = 0.f;
        if (cc < 20 && (unsigned)gy < 64u && (unsigned)gx < 64u)
            val = X[((size_t)bb * 256 + c0 + ch) * NPX + gy * 64 + gx];
        xt[idx] = val;
    }
    int ylq = tid >> 4, xlq = tid & 15;
    int yl = ty0 + ylq, xl = tx0 + xlq;
    int px = yl * 64 + xl;
    float wv[100];
    #pragma unroll
    for (int j = 0; j < 100; ++j)
        wv[j] = wn[((size_t)bb * 100 + j) * NPX + px];
    __syncthreads();
    for (int ch = 0; ch < 16; ++ch) {
        float x[25];
        #pragma unroll
        for (int ki = 0; ki < 5; ++ki)
            #pragma unroll
            for (int kj = 0; kj < 5; ++kj)
                x[ki * 5 + kj] = xt[ch * 480 + (ylq + ki) * 24 + (xlq + kj)];
        float a0 = 0.f, a1 = 0.f, a2 = 0.f, a3 = 0.f;
        #pragma unroll
        for (int k = 0; k < 25; ++k) {
            a0 += wv[k]      * x[k];
            a1 += wv[25 + k] * x[k];
            a2 += wv[50 + k] * x[k];
            a3 += wv[75 + k] * x[k];
        }
        float* ob = out + ((size_t)(bb * 256 + c0 + ch) * H2 + 2 * yl) * W2 + 2 * xl;
        *(float2*)ob        = make_float2(a0, a1);
        *(float2*)(ob + W2) = make_float2(a2, a3);
    }
}

extern "C" void kernel_launch(void* const* d_in, const int* in_sizes, int n_in,
                              void* d_out, int out_size, void* d_ws, size_t ws_size,
                              hipStream_t stream)
{
    const float* X  = (const float*)d_in[0];
    const float* cw = (const float*)d_in[1];
    const float* cg = (const float*)d_in[2];
    const float* cb = (const float*)d_in[3];
    const float* cm = (const float*)d_in[4];
    const float* cv = (const float*)d_in[5];
    const float* ew = (const float*)d_in[6];
    const float* eg = (const float*)d_in[7];
    const float* eb = (const float*)d_in[8];
    const float* em = (const float*)d_in[9];
    const float* ev = (const float*)d_in[10];
    const float* pp = (const float*)d_in[11];
    float* out = (float*)d_out;

    float* ws  = (float*)d_ws;
    float* mid = ws;                        // 2*64*4096   floats (BN+ReLU applied)
    float* enc = ws + 524288;               // 2*100*4096  floats (raw conv sums)
    float* wn  = ws + 524288 + 819200;      // 2*100*4096  floats

    k1_conv1x1<<<dim3(128, 2), 256, 0, stream>>>(X, cw, cg, cb, cm, cv, mid);
    k2a_conv3x3<<<dim3(25, 32), 256, 0, stream>>>(mid, ew, enc);
    k2b_softmax<<<dim3(512), 64, 0, stream>>>(enc, eg, eb, em, ev, pp, wn);
    k3_carafe<<<dim3(32, 16), 256, 0, stream>>>(X, wn, out);
}

// Round 6
// 185.928 us; speedup vs baseline: 1.1197x; 1.1197x over previous
//
#include <hip/hip_runtime.h>
#include <math.h>

#define NPX 4096          // 64*64 low-res pixels per batch
#define H2 128
#define W2 128
#define PP 66             // padded mid plane: 66x66, interior 1..64

// K1: 1x1 conv (256->64) + BN + ReLU, writing into padded mid_p[b][co][66][66].
// grid (128 = 2b x 64 rows, 8 co-groups), block 256 = 4 waves = 4 ci-quarters.
// lane = x. Weights wave-uniform -> s_load. One barrier (ci reduce via LDS).
__global__ __launch_bounds__(256) void k1_conv1x1(
    const float* __restrict__ X, const float* __restrict__ w,
    const float* __restrict__ g, const float* __restrict__ bt,
    const float* __restrict__ m, const float* __restrict__ var,
    float* __restrict__ mid_p)
{
    __shared__ float red[3 * 8 * 64];   // 6 KB
    int tid = threadIdx.x;
    int x = tid & 63;
    int ciq = __builtin_amdgcn_readfirstlane(tid >> 6);   // 0..3
    int bx = blockIdx.x;
    int bb = bx >> 6, y = bx & 63;
    int co0 = blockIdx.y * 8;
    int ci0 = ciq * 64;

    const float* xp = X + ((size_t)(bb * 256 + ci0)) * NPX + y * 64 + x;
    const float* wp = w + (size_t)co0 * 256 + ci0;   // uniform -> s_load

    float acc[8];
    #pragma unroll
    for (int j = 0; j < 8; ++j) acc[j] = 0.f;

    #pragma unroll 4
    for (int ci = 0; ci < 64; ++ci) {
        float xv = xp[(size_t)ci * NPX];
        #pragma unroll
        for (int j = 0; j < 8; ++j)
            acc[j] += xv * wp[j * 256 + ci];
    }

    if (ciq > 0) {
        #pragma unroll
        for (int j = 0; j < 8; ++j)
            red[((ciq - 1) * 8 + j) * 64 + x] = acc[j];
    }
    __syncthreads();
    if (ciq == 0) {
        #pragma unroll
        for (int j = 0; j < 8; ++j) {
            float a = acc[j] + red[(0 * 8 + j) * 64 + x]
                             + red[(1 * 8 + j) * 64 + x]
                             + red[(2 * 8 + j) * 64 + x];
            int co = co0 + j;
            float inv = g[co] * rsqrtf(var[co] + 1e-5f);
            a = fmaxf(a * inv + (bt[co] - m[co] * inv), 0.f);
            mid_p[((size_t)(bb * 64 + co) * PP + (y + 1)) * PP + (x + 1)] = a;
        }
    }
}

// K2a: 3x3 conv (64->100) streaming directly from padded mid_p (L2-resident).
// grid (128 = 2b x 64 rows, 5 co-groups of 20), block 256 = 4 ci-quarter waves.
// lane = x. No bounds checks (padding), no staging, weights via s_load,
// one barrier for the ci reduce.
__global__ __launch_bounds__(256) void k2a_conv3x3(
    const float* __restrict__ mid_p, const float* __restrict__ ew,
    float* __restrict__ enc)
{
    __shared__ float red[3 * 20 * 64];   // 15.4 KB
    int tid = threadIdx.x;
    int x = tid & 63;
    int ciq = __builtin_amdgcn_readfirstlane(tid >> 6);   // 0..3
    int bx = blockIdx.x;
    int bb = bx >> 6, y = bx & 63;
    int co0 = blockIdx.y * 20;

    float acc[20];
    #pragma unroll
    for (int j = 0; j < 20; ++j) acc[j] = 0.f;

    const float* wb = ew + ((size_t)co0 * 64 + ciq * 16) * 9;   // uniform

    #pragma unroll 2
    for (int ci = 0; ci < 16; ++ci) {
        const float* P = mid_p + (((size_t)(bb * 64 + ciq * 16 + ci)) * PP + y) * PP + x;
        float v0 = P[0],       v1 = P[1],       v2 = P[2];
        float v3 = P[PP],      v4 = P[PP + 1],  v5 = P[PP + 2];
        float v6 = P[2 * PP],  v7 = P[2 * PP + 1], v8 = P[2 * PP + 2];
        const float* wp = wb + ci * 9;          // j stride = 64*9 = 576
        #pragma unroll
        for (int j = 0; j < 20; ++j) {
            const float* wj = wp + j * 576;
            acc[j] += v0 * wj[0] + v1 * wj[1] + v2 * wj[2]
                    + v3 * wj[3] + v4 * wj[4] + v5 * wj[5]
                    + v6 * wj[6] + v7 * wj[7] + v8 * wj[8];
        }
    }

    if (ciq > 0) {
        #pragma unroll
        for (int j = 0; j < 20; ++j)
            red[((ciq - 1) * 20 + j) * 64 + x] = acc[j];
    }
    __syncthreads();
    if (ciq == 0) {
        #pragma unroll
        for (int j = 0; j < 20; ++j) {
            float a = acc[j] + red[(0 * 20 + j) * 64 + x]
                             + red[(1 * 20 + j) * 64 + x]
                             + red[(2 * 20 + j) * 64 + x];
            enc[((size_t)bb * 100 + co0 + j) * NPX + y * 64 + x] = a;
        }
    }
}

// K2b: BN + clamp + pow + softmax over 25 taps. wn layout [b][s*25+k][px].
__global__ __launch_bounds__(64) void k2b_softmax(
    const float* __restrict__ enc,
    const float* __restrict__ g, const float* __restrict__ bt,
    const float* __restrict__ m, const float* __restrict__ var,
    const float* __restrict__ power_p,
    float* __restrict__ wn)
{
    int s = blockIdx.x & 3;
    int p = (blockIdx.x >> 2) * 64 + threadIdx.x;
    int bb = p >> 12, sp = p & (NPX - 1);
    float pw = fmaxf(power_p[0], 1e-5f);
    float tv[25];
    float mx = -1e30f;
    #pragma unroll
    for (int k = 0; k < 25; ++k) {
        int co = 4 * k + s;
        float inv = g[co] * rsqrtf(var[co] + 1e-5f);
        float e = enc[((size_t)bb * 100 + co) * NPX + sp] * inv + (bt[co] - m[co] * inv);
        e = fmaxf(e, 1e-5f);
        float xq = exp2f(pw * log2f(e));
        tv[k] = xq;
        mx = fmaxf(mx, xq);
    }
    float sum = 0.f;
    #pragma unroll
    for (int k = 0; k < 25; ++k) {
        float e = expf(tv[k] - mx);
        tv[k] = e;
        sum += e;
    }
    float r = 1.0f / sum;
    #pragma unroll
    for (int k = 0; k < 25; ++k)
        wn[((size_t)bb * 100 + s * 25 + k) * NPX + sp] = tv[k] * r;
}

// K3: reassembly. grid (2b x 16 tiles, 16 ch-chunks), block 256 = 16x16 low-px.
// LDS tile layout xt[r][ch][32] with row stride 520 words (twist 8): compute
// reads hit each bank exactly twice (free). Shift-only staging indexing.
__global__ __launch_bounds__(256) void k3_carafe(
    const float* __restrict__ X, const float* __restrict__ wn,
    float* __restrict__ out)
{
    __shared__ float xt[20 * 520];   // 41.6 KB
    int tid = threadIdx.x;
    int bx = blockIdx.x;
    int bb = bx >> 4;
    int t = bx & 15;
    int ty0 = (t >> 2) * 16, tx0 = (t & 3) * 16;
    int c0 = blockIdx.y * 16;

    int ylq = tid >> 4, xlq = tid & 15;
    int yl = ty0 + ylq, xl = tx0 + xlq;
    int px = yl * 64 + xl;

    // issue the 100 coalesced weight loads first (independent of LDS)
    float wv[100];
    #pragma unroll
    for (int j = 0; j < 100; ++j)
        wv[j] = wn[((size_t)bb * 100 + j) * NPX + px];

    // staging: idx -> c = idx&31, ch = (idx>>5)&15, r = idx>>9  (all shifts)
    #pragma unroll
    for (int i = 0; i < 40; ++i) {          // 20 r x 16 ch x 32 c = 10240
        int idx = tid + 256 * i;
        int c = idx & 31;
        int ch = (idx >> 5) & 15;
        int r = idx >> 9;
        int gy = ty0 + r - 2, gx = tx0 + c - 2;
        float val = 0.f;
        if (c < 20 && (unsigned)gy < 64u && (unsigned)gx < 64u)
            val = X[((size_t)(bb * 256 + c0 + ch)) * NPX + gy * 64 + gx];
        xt[r * 520 + ch * 32 + c] = val;
    }
    __syncthreads();

    for (int ch = 0; ch < 16; ++ch) {
        float xv[25];
        #pragma unroll
        for (int ki = 0; ki < 5; ++ki)
            #pragma unroll
            for (int kj = 0; kj < 5; ++kj)
                xv[ki * 5 + kj] = xt[(ylq + ki) * 520 + ch * 32 + (xlq + kj)];
        float a0 = 0.f, a1 = 0.f, a2 = 0.f, a3 = 0.f;
        #pragma unroll
        for (int k = 0; k < 25; ++k) {
            a0 += wv[k]      * xv[k];
            a1 += wv[25 + k] * xv[k];
            a2 += wv[50 + k] * xv[k];
            a3 += wv[75 + k] * xv[k];
        }
        float* ob = out + ((size_t)(bb * 256 + c0 + ch) * H2 + 2 * yl) * W2 + 2 * xl;
        *(float2*)ob        = make_float2(a0, a1);
        *(float2*)(ob + W2) = make_float2(a2, a3);
    }
}

extern "C" void kernel_launch(void* const* d_in, const int* in_sizes, int n_in,
                              void* d_out, int out_size, void* d_ws, size_t ws_size,
                              hipStream_t stream)
{
    const float* X  = (const float*)d_in[0];
    const float* cw = (const float*)d_in[1];
    const float* cg = (const float*)d_in[2];
    const float* cb = (const float*)d_in[3];
    const float* cm = (const float*)d_in[4];
    const float* cv = (const float*)d_in[5];
    const float* ew = (const float*)d_in[6];
    const float* eg = (const float*)d_in[7];
    const float* eb = (const float*)d_in[8];
    const float* em = (const float*)d_in[9];
    const float* ev = (const float*)d_in[10];
    const float* pp = (const float*)d_in[11];
    float* out = (float*)d_out;

    float* ws   = (float*)d_ws;
    float* midp = ws;                         // 2*64*66*66 = 557,568 floats (padded)
    float* enc  = ws + 557568;                // 2*100*4096 = 819,200 floats
    float* wn   = ws + 557568 + 819200;       // 2*100*4096 = 819,200 floats

    hipMemsetAsync(midp, 0, 557568 * sizeof(float), stream);   // zero pad borders
    k1_conv1x1<<<dim3(128, 8), 256, 0, stream>>>(X, cw, cg, cb, cm, cv, midp);
    k2a_conv3x3<<<dim3(128, 5), 256, 0, stream>>>(midp, ew, enc);
    k2b_softmax<<<dim3(512), 64, 0, stream>>>(enc, eg, eb, em, ev, pp, wn);
    k3_carafe<<<dim3(32, 16), 256, 0, stream>>>(X, wn, out);
}

// Round 7
// 157.279 us; speedup vs baseline: 1.3237x; 1.1822x over previous
//
#include <hip/hip_runtime.h>
#include <math.h>

#define NPX 4096          // 64*64 low-res pixels per batch
#define H2 128
#define W2 128
#define PP 66             // padded mid plane: 66x66, interior 1..64

// K1: 1x1 conv (256->64) + BN + ReLU into padded mid_p[b][co][66][66].
// grid (128 = 2b x 64 rows, 16 co-groups of 4), block 256 = 4 ci-quarter waves.
// lane = x. 8192 waves = 8/SIMD. Weights wave-uniform -> s_load.
__global__ __launch_bounds__(256) void k1_conv1x1(
    const float* __restrict__ X, const float* __restrict__ w,
    const float* __restrict__ g, const float* __restrict__ bt,
    const float* __restrict__ m, const float* __restrict__ var,
    float* __restrict__ mid_p)
{
    __shared__ float red[3 * 4 * 64];   // 3 KB
    int tid = threadIdx.x;
    int x = tid & 63;
    int ciq = __builtin_amdgcn_readfirstlane(tid >> 6);   // 0..3
    int bx = blockIdx.x;
    int bb = bx >> 6, y = bx & 63;
    int co0 = blockIdx.y * 4;
    int ci0 = ciq * 64;

    const float* xp = X + ((size_t)(bb * 256 + ci0)) * NPX + y * 64 + x;
    const float* wp = w + (size_t)co0 * 256 + ci0;   // uniform -> s_load

    float acc[4] = {0.f, 0.f, 0.f, 0.f};

    #pragma unroll 8
    for (int ci = 0; ci < 64; ++ci) {
        float xv = xp[(size_t)ci * NPX];
        #pragma unroll
        for (int j = 0; j < 4; ++j)
            acc[j] += xv * wp[j * 256 + ci];
    }

    if (ciq > 0) {
        #pragma unroll
        for (int j = 0; j < 4; ++j)
            red[((ciq - 1) * 4 + j) * 64 + x] = acc[j];
    }
    __syncthreads();
    if (ciq == 0) {
        #pragma unroll
        for (int j = 0; j < 4; ++j) {
            float a = acc[j] + red[(0 * 4 + j) * 64 + x]
                             + red[(1 * 4 + j) * 64 + x]
                             + red[(2 * 4 + j) * 64 + x];
            int co = co0 + j;
            float inv = g[co] * rsqrtf(var[co] + 1e-5f);
            a = fmaxf(a * inv + (bt[co] - m[co] * inv), 0.f);
            mid_p[((size_t)(bb * 64 + co) * PP + (y + 1)) * PP + (x + 1)] = a;
        }
    }
}

// K2a: 3x3 conv (64->100) streaming from padded mid_p (L2-resident).
// grid (128 = 2b x 64 rows, 10 co-groups of 10), block 256 = 4 ci-quarter waves.
// 5120 waves = 5/SIMD. lane = x. No bounds checks, weights s_load, one barrier.
__global__ __launch_bounds__(256) void k2a_conv3x3(
    const float* __restrict__ mid_p, const float* __restrict__ ew,
    float* __restrict__ enc)
{
    __shared__ float red[3 * 10 * 64];   // 7.7 KB
    int tid = threadIdx.x;
    int x = tid & 63;
    int ciq = __builtin_amdgcn_readfirstlane(tid >> 6);   // 0..3
    int bx = blockIdx.x;
    int bb = bx >> 6, y = bx & 63;
    int co0 = blockIdx.y * 10;

    float acc[10];
    #pragma unroll
    for (int j = 0; j < 10; ++j) acc[j] = 0.f;

    const float* wb = ew + ((size_t)co0 * 64 + ciq * 16) * 9;   // uniform

    #pragma unroll 2
    for (int ci = 0; ci < 16; ++ci) {
        const float* P = mid_p + (((size_t)(bb * 64 + ciq * 16 + ci)) * PP + y) * PP + x;
        float v0 = P[0],       v1 = P[1],          v2 = P[2];
        float v3 = P[PP],      v4 = P[PP + 1],     v5 = P[PP + 2];
        float v6 = P[2 * PP],  v7 = P[2 * PP + 1], v8 = P[2 * PP + 2];
        const float* wp = wb + ci * 9;          // j stride = 64*9 = 576
        #pragma unroll
        for (int j = 0; j < 10; ++j) {
            const float* wj = wp + j * 576;
            acc[j] += v0 * wj[0] + v1 * wj[1] + v2 * wj[2]
                    + v3 * wj[3] + v4 * wj[4] + v5 * wj[5]
                    + v6 * wj[6] + v7 * wj[7] + v8 * wj[8];
        }
    }

    if (ciq > 0) {
        #pragma unroll
        for (int j = 0; j < 10; ++j)
            red[((ciq - 1) * 10 + j) * 64 + x] = acc[j];
    }
    __syncthreads();
    if (ciq == 0) {
        #pragma unroll
        for (int j = 0; j < 10; ++j) {
            float a = acc[j] + red[(0 * 10 + j) * 64 + x]
                             + red[(1 * 10 + j) * 64 + x]
                             + red[(2 * 10 + j) * 64 + x];
            enc[((size_t)bb * 100 + co0 + j) * NPX + y * 64 + x] = a;
        }
    }
}

// K2b: BN + clamp + pow + softmax over 25 taps. wn layout [b][s*25+k][px].
__global__ __launch_bounds__(64) void k2b_softmax(
    const float* __restrict__ enc,
    const float* __restrict__ g, const float* __restrict__ bt,
    const float* __restrict__ m, const float* __restrict__ var,
    const float* __restrict__ power_p,
    float* __restrict__ wn)
{
    int s = blockIdx.x & 3;
    int p = (blockIdx.x >> 2) * 64 + threadIdx.x;
    int bb = p >> 12, sp = p & (NPX - 1);
    float pw = fmaxf(power_p[0], 1e-5f);
    float tv[25];
    float mx = -1e30f;
    #pragma unroll
    for (int k = 0; k < 25; ++k) {
        int co = 4 * k + s;
        float inv = g[co] * rsqrtf(var[co] + 1e-5f);
        float e = enc[((size_t)bb * 100 + co) * NPX + sp] * inv + (bt[co] - m[co] * inv);
        e = fmaxf(e, 1e-5f);
        float xq = exp2f(pw * log2f(e));
        tv[k] = xq;
        mx = fmaxf(mx, xq);
    }
    float sum = 0.f;
    #pragma unroll
    for (int k = 0; k < 25; ++k) {
        float e = expf(tv[k] - mx);
        tv[k] = e;
        sum += e;
    }
    float r = 1.0f / sum;
    #pragma unroll
    for (int k = 0; k < 25; ++k)
        wn[((size_t)bb * 100 + s * 25 + k) * NPX + sp] = tv[k] * r;
}

// K3: reassembly, row-based. grid (128 = 2b x 64 low-res rows, 16 ch-groups),
// block 256 = 4 waves; wave = sub-position s=(dy,dx), lane = px in the row.
// Wave holds its 25 wn weights in VGPRs (coalesced global loads); X halo
// (16ch x 5r x 72) in 23 KB LDS. 8192 waves total.
__global__ __launch_bounds__(256) void k3_carafe(
    const float* __restrict__ X, const float* __restrict__ wn,
    float* __restrict__ out)
{
    __shared__ float xt[16 * 5 * 72];   // 23 KB
    int tid = threadIdx.x;
    int px = tid & 63;
    int s = __builtin_amdgcn_readfirstlane(tid >> 6);   // 0..3
    int dy = s >> 1, dx = s & 1;
    int bx = blockIdx.x;
    int bb = bx >> 6, y = bx & 63;
    int c0 = blockIdx.y * 16;

    // 25 per-wave weights, coalesced (lane = px)
    float wv[25];
    const float* wsrc = wn + ((size_t)bb * 100 + s * 25) * NPX + y * 64 + px;
    #pragma unroll
    for (int k = 0; k < 25; ++k)
        wv[k] = wsrc[(size_t)k * NPX];

    // stage X halo: [ch][r][72], r = y-2..y+2, c stores gx = c-2
    for (int idx = tid; idx < 5760; idx += 256) {
        int ch = idx / 360;
        int rem = idx - ch * 360;
        int r = rem / 72, c = rem - r * 72;
        int gy = y + r - 2, gx = c - 2;
        float val = 0.f;
        if (c < 68 && (unsigned)gy < 64u && (unsigned)gx < 64u)
            val = X[((size_t)(bb * 256 + c0 + ch)) * NPX + gy * 64 + gx];
        xt[idx] = val;
    }
    __syncthreads();

    int y2 = 2 * y + dy, x2 = 2 * px + dx;
    float* ob = out + ((size_t)(bb * 256 + c0) * H2 + y2) * W2 + x2;
    for (int ch = 0; ch < 16; ++ch) {
        const float* xb = &xt[ch * 360 + px];
        float a = 0.f;
        #pragma unroll
        for (int ki = 0; ki < 5; ++ki)
            #pragma unroll
            for (int kj = 0; kj < 5; ++kj)
                a += wv[ki * 5 + kj] * xb[ki * 72 + kj];
        ob[(size_t)ch * H2 * W2] = a;
    }
}

extern "C" void kernel_launch(void* const* d_in, const int* in_sizes, int n_in,
                              void* d_out, int out_size, void* d_ws, size_t ws_size,
                              hipStream_t stream)
{
    const float* X  = (const float*)d_in[0];
    const float* cw = (const float*)d_in[1];
    const float* cg = (const float*)d_in[2];
    const float* cb = (const float*)d_in[3];
    const float* cm = (const float*)d_in[4];
    const float* cv = (const float*)d_in[5];
    const float* ew = (const float*)d_in[6];
    const float* eg = (const float*)d_in[7];
    const float* eb = (const float*)d_in[8];
    const float* em = (const float*)d_in[9];
    const float* ev = (const float*)d_in[10];
    const float* pp = (const float*)d_in[11];
    float* out = (float*)d_out;

    float* ws   = (float*)d_ws;
    float* midp = ws;                         // 2*64*66*66 = 557,568 floats (padded)
    float* enc  = ws + 557568;                // 2*100*4096 = 819,200 floats
    float* wn   = ws + 557568 + 819200;       // 2*100*4096 = 819,200 floats

    hipMemsetAsync(midp, 0, 557568 * sizeof(float), stream);   // zero pad borders
    k1_conv1x1<<<dim3(128, 16), 256, 0, stream>>>(X, cw, cg, cb, cm, cv, midp);
    k2a_conv3x3<<<dim3(128, 10), 256, 0, stream>>>(midp, ew, enc);
    k2b_softmax<<<dim3(512), 64, 0, stream>>>(enc, eg, eb, em, ev, pp, wn);
    k3_carafe<<<dim3(128, 16), 256, 0, stream>>>(X, wn, out);
}